// Round 5
// baseline (1196.132 us; speedup 1.0000x reference)
//
#include <hip/hip_runtime.h>

#define N_NODES 50000
#define N_EDGES 400000
#define N_GRAPHS 64
#define EMB 64
#define H 128
#define EPS 1e-5f

typedef __attribute__((ext_vector_type(8))) short bf16x8;
typedef __attribute__((ext_vector_type(4))) float f32x4;

__device__ __forceinline__ unsigned short f2b(float f) {
    unsigned int u = __builtin_bit_cast(unsigned int, f);
    unsigned int r = (u + 0x7fff + ((u >> 16) & 1)) >> 16;  // RNE
    return (unsigned short)r;
}

// ---------------- CSR build ----------------

__global__ void count_deg_kernel(const int* __restrict__ dst, int* __restrict__ deg) {
    int rel = blockIdx.y;
    int e = blockIdx.x * 256 + threadIdx.x;
    if (e < N_EDGES) atomicAdd(&deg[rel * N_NODES + dst[rel * N_EDGES + e]], 1);
}

__global__ void scan_kernel(const int* __restrict__ deg, int* __restrict__ row_ptr) {
    int rel = blockIdx.x;
    const int* d = deg + rel * N_NODES;
    int* rp = row_ptr + rel * (N_NODES + 1);
    __shared__ int sm[1024];
    __shared__ int carry;
    if (threadIdx.x == 0) carry = 0;
    __syncthreads();
    for (int base = 0; base < N_NODES; base += 1024) {
        int i = base + (int)threadIdx.x;
        int v = (i < N_NODES) ? d[i] : 0;
        sm[threadIdx.x] = v;
        __syncthreads();
        for (int off = 1; off < 1024; off <<= 1) {
            int t = (threadIdx.x >= off) ? sm[threadIdx.x - off] : 0;
            __syncthreads();
            sm[threadIdx.x] += t;
            __syncthreads();
        }
        int incl = sm[threadIdx.x];
        if (i < N_NODES) rp[i] = carry + incl - v;
        __syncthreads();
        if (threadIdx.x == 1023) carry += incl;
        __syncthreads();
    }
    if (threadIdx.x == 0) rp[N_NODES] = carry;
}

__global__ void init_cur_kernel(const int* __restrict__ row_ptr, int* __restrict__ cur) {
    int i = blockIdx.x * 256 + threadIdx.x;
    if (i < 3 * N_NODES) {
        int rel = i / N_NODES, n = i - rel * N_NODES;
        cur[i] = row_ptr[rel * (N_NODES + 1) + n];
    }
}

__global__ void fill_kernel(const int* __restrict__ src, const int* __restrict__ dst,
                            int* __restrict__ cur, int* __restrict__ edge_src) {
    int rel = blockIdx.y;
    int e = blockIdx.x * 256 + threadIdx.x;
    if (e < N_EDGES) {
        int dn = dst[rel * N_EDGES + e];
        int pos = atomicAdd(&cur[rel * N_NODES + dn], 1);
        edge_src[rel * N_EDGES + pos] = src[rel * N_EDGES + e];
    }
}

// ---------------- Embedding gather -> bf16 x0 ----------------

__global__ void embed_kernel(const int* __restrict__ h_idx, const int* __restrict__ p_idx,
                             const int* __restrict__ hp_idx,
                             const float* __restrict__ emb_h, const float* __restrict__ emb_p,
                             const float* __restrict__ emb_hp,
                             unsigned short* __restrict__ x) {
    int rel = blockIdx.y;
    int i = blockIdx.x * 256 + threadIdx.x;  // 8-col units
    if (i >= N_NODES * EMB / 8) return;
    int n = i / (EMB / 8), c8 = (i % (EMB / 8)) * 8;
    const int* idx = rel == 0 ? h_idx : (rel == 1 ? p_idx : hp_idx);
    const float* emb = rel == 0 ? emb_h : (rel == 1 ? emb_p : emb_hp);
    const float* e = emb + (size_t)idx[n] * EMB + c8;
    unsigned short o[8];
#pragma unroll
    for (int j = 0; j < 8; j++) o[j] = f2b(e[j]);
    *(uint4*)&x[(size_t)rel * N_NODES * EMB + (size_t)n * EMB + c8] = *(uint4*)o;
}

// ---- Fused aggregate + MFMA GEMM ----
// Phase 1: block gathers neighbor means for its 128 rows into LDS (BN fold, deg0->0).
// Phase 2: hp = PReLU([x | nm_lds] @ Wbt^T + bias); fp32 column stats.
// Self half staged via At; neigh half read from nm_lds; B frags direct from L2.

template <int KX, bool FOLD>
__global__ __launch_bounds__(256) void fused_gemm_kernel(
        const unsigned short* __restrict__ x,      // [rel][N][KX] bf16 (raw hp / x0)
        const int* __restrict__ row_ptr,
        const int* __restrict__ edge_src,
        const float* __restrict__ st,              // [rel][2][H] (FOLD only)
        const unsigned short* __restrict__ Wbt,    // [rel][H cols][2*KX] bf16
        const float* __restrict__ bias,            // [rel][H]
        const float* __restrict__ alpha,           // [rel][H]
        unsigned short* __restrict__ out,          // [rel][N][H] bf16 (pre-BN)
        float* __restrict__ stats) {
    const int KTOT = 2 * KX;
    const int LDN = KX + 8;                        // pad keeps (LDN/8) odd -> low conflicts
    int rel = blockIdx.y;
    int row0 = blockIdx.x * 128;
    const unsigned short* xr = x + (size_t)rel * N_NODES * KX;
    const unsigned short* W = Wbt + (size_t)rel * H * KTOT;
    unsigned short* o = out + (size_t)rel * N_NODES * H;

    __shared__ __align__(16) short nm[128 * LDN];
    __shared__ __align__(16) short At[128][40];

    int tid = threadIdx.x;

    // ---- phase 1: aggregate this block's 128 rows into nm ----
    {
        const int TPN = KX / 8;        // threads per node
        const int NPB = 256 / TPN;     // nodes per batch
        int c8 = (tid % TPN) * 8;
        int nloc = tid / TPN;
        const int* rp = row_ptr + rel * (N_NODES + 1);
        const int* es = edge_src + rel * N_EDGES;
#pragma unroll
        for (int base = 0; base < 128; base += NPB) {
            int lr = base + nloc;
            int node = row0 + lr;
            float acc[8];
#pragma unroll
            for (int j = 0; j < 8; j++) acc[j] = 0.f;
            int deg = 0;
            if (node < N_NODES) {
                int s0 = rp[node], s1 = rp[node + 1];
                deg = s1 - s0;
#define ACCUM(V)                                                                  \
    {                                                                             \
        unsigned int w[4] = {(V).x, (V).y, (V).z, (V).w};                         \
        _Pragma("unroll") for (int j = 0; j < 4; j++) {                           \
            acc[2 * j] += __builtin_bit_cast(float, w[j] << 16);                  \
            acc[2 * j + 1] += __builtin_bit_cast(float, w[j] & 0xffff0000u);      \
        }                                                                         \
    }
                int e = s0;
                for (; e + 4 <= s1; e += 4) {
                    int i0 = es[e], i1 = es[e + 1], i2 = es[e + 2], i3 = es[e + 3];
                    uint4 v0 = *(const uint4*)&xr[(size_t)i0 * KX + c8];
                    uint4 v1 = *(const uint4*)&xr[(size_t)i1 * KX + c8];
                    uint4 v2 = *(const uint4*)&xr[(size_t)i2 * KX + c8];
                    uint4 v3 = *(const uint4*)&xr[(size_t)i3 * KX + c8];
                    ACCUM(v0) ACCUM(v1) ACCUM(v2) ACCUM(v3)
                }
                for (; e < s1; e++) {
                    uint4 v0 = *(const uint4*)&xr[(size_t)es[e] * KX + c8];
                    ACCUM(v0)
                }
#undef ACCUM
            }
            float inv = 1.f / (float)max(deg, 1);
            unsigned short ov[8];
#pragma unroll
            for (int j = 0; j < 8; j++) {
                float m = acc[j] * inv;
                if (FOLD) {
                    float s = st[rel * 2 * H + c8 + j];
                    float t = st[rel * 2 * H + H + c8 + j];
                    m = s * m + t;
                }
                ov[j] = (deg > 0) ? f2b(m) : (unsigned short)0;
            }
            *(uint4*)&nm[lr * LDN + c8] = *(uint4*)ov;
        }
    }
    __syncthreads();

    // ---- phase 2: GEMM ----
    int lane = tid & 63;
    int wave = tid >> 6;
    int wr = wave >> 1, wc = wave & 1;
    int l15 = lane & 15;
    int koff = (lane >> 4) * 8;

    f32x4 acc[4][4];
#pragma unroll
    for (int m = 0; m < 4; m++)
#pragma unroll
        for (int n = 0; n < 4; n++) acc[m][n] = (f32x4){0.f, 0.f, 0.f, 0.f};

    int seg = tid & 3;
    int rloc = tid >> 2;

    // self half (k = 0..KX): staged through At
    for (int kc = 0; kc < KX; kc += 32) {
#pragma unroll
        for (int i = 0; i < 2; i++) {
            int r = i * 64 + rloc;
            int gr = row0 + r;
            uint4 v = make_uint4(0u, 0u, 0u, 0u);
            if (gr < N_NODES) v = *(const uint4*)&xr[(size_t)gr * KX + kc + seg * 8];
            *(uint4*)&At[r][seg * 8] = v;
        }
        __syncthreads();
        bf16x8 a[4], b[4];
#pragma unroll
        for (int m = 0; m < 4; m++) a[m] = *(const bf16x8*)&At[wr * 64 + m * 16 + l15][koff];
#pragma unroll
        for (int n = 0; n < 4; n++)
            b[n] = *(const bf16x8*)&W[(size_t)(wc * 64 + n * 16 + l15) * KTOT + kc + koff];
#pragma unroll
        for (int m = 0; m < 4; m++)
#pragma unroll
            for (int n = 0; n < 4; n++)
                acc[m][n] = __builtin_amdgcn_mfma_f32_16x16x32_bf16(a[m], b[n], acc[m][n], 0, 0, 0);
        __syncthreads();
    }
    // neigh half (k = KX..2KX): A frags straight from nm (read-only, no syncs)
    for (int kc = 0; kc < KX; kc += 32) {
        bf16x8 a[4], b[4];
#pragma unroll
        for (int m = 0; m < 4; m++) {
            int r = wr * 64 + m * 16 + l15;
            a[m] = *(const bf16x8*)&nm[r * LDN + kc + koff];
        }
#pragma unroll
        for (int n = 0; n < 4; n++)
            b[n] = *(const bf16x8*)&W[(size_t)(wc * 64 + n * 16 + l15) * KTOT + KX + kc + koff];
#pragma unroll
        for (int m = 0; m < 4; m++)
#pragma unroll
            for (int n = 0; n < 4; n++)
                acc[m][n] = __builtin_amdgcn_mfma_f32_16x16x32_bf16(a[m], b[n], acc[m][n], 0, 0, 0);
    }

    // epilogue: bias + PReLU, bf16 store, fp32 column stats
    float bs[4], as_[4];
#pragma unroll
    for (int n = 0; n < 4; n++) {
        int col = wc * 64 + n * 16 + l15;
        bs[n] = bias[rel * H + col];
        as_[n] = alpha[rel * H + col];
    }
    float csum[4] = {0.f, 0.f, 0.f, 0.f}, cssq[4] = {0.f, 0.f, 0.f, 0.f};
    int rbase = row0 + wr * 64 + (lane >> 4) * 4;
#pragma unroll
    for (int m = 0; m < 4; m++) {
#pragma unroll
        for (int j = 0; j < 4; j++) {
            int r = rbase + m * 16 + j;
            if (r >= N_NODES) continue;
#pragma unroll
            for (int n = 0; n < 4; n++) {
                float v = acc[m][n][j] + bs[n];
                v = v > 0.f ? v : as_[n] * v;
                o[(size_t)r * H + wc * 64 + n * 16 + l15] = f2b(v);
                csum[n] += v;
                cssq[n] += v * v;
            }
        }
    }
    __syncthreads();
    float* smS = (float*)&At[0][0];   // 128 cols x 8 contributors = 4 KB
    float* smQ = (float*)&nm[0];
    int contrib = wr * 4 + (lane >> 4);
#pragma unroll
    for (int n = 0; n < 4; n++) {
        int col = wc * 64 + n * 16 + l15;
        smS[col * 8 + contrib] = csum[n];
        smQ[col * 8 + contrib] = cssq[n];
    }
    __syncthreads();
    if (tid < 128) {
        float s = 0.f, q = 0.f;
#pragma unroll
        for (int i = 0; i < 8; i++) { s += smS[tid * 8 + i]; q += smQ[tid * 8 + i]; }
        atomicAdd(&stats[rel * 256 + tid], s);
        atomicAdd(&stats[rel * 256 + 128 + tid], q);
    }
}

// ---------------- BN stats -> affine (s,t) ----------------

__global__ void finalize_kernel(const float* __restrict__ stats,
                                const float* __restrict__ gamma, const float* __restrict__ beta,
                                float* __restrict__ st) {
    int rel = blockIdx.x, c = threadIdx.x;
    const float invN = 1.f / N_NODES;
    float mu = stats[rel * 256 + c] * invN;
    float var = stats[rel * 256 + 128 + c] * invN - mu * mu;
    float s = gamma[rel * H + c] * rsqrtf(var + EPS);
    st[rel * 2 * H + c] = s;
    st[rel * 2 * H + H + c] = beta[rel * H + c] - mu * s;
}

// ---------------- Weight prep ----------------

__global__ void prep1_kernel(const float* __restrict__ Wself, const float* __restrict__ Wneigh,
                             unsigned short* __restrict__ Wbt) {
    int idx = blockIdx.x * 256 + threadIdx.x;
    if (idx >= 3 * H * 128) return;
    int rel = idx / (H * 128), rem = idx % (H * 128);
    int c = rem / 128, k = rem % 128;
    float v = (k < 64) ? Wself[((size_t)rel * 64 + k) * H + c]
                       : Wneigh[((size_t)rel * 64 + (k - 64)) * H + c];
    Wbt[idx] = f2b(v);
}

__global__ void prep_w_kernel(const float* __restrict__ Wself, const float* __restrict__ Wneigh,
                              const float* __restrict__ st, unsigned short* __restrict__ Wbt) {
    int idx = blockIdx.x * 256 + threadIdx.x;
    if (idx >= 3 * H * 256) return;
    int rel = idx / (H * 256), rem = idx % (H * 256);
    int c = rem / 256, k = rem % 256;
    float v;
    if (k < 128) v = st[rel * 2 * H + k] * Wself[((size_t)rel * H + k) * H + c];
    else         v = Wneigh[((size_t)rel * H + (k - 128)) * H + c];
    Wbt[idx] = f2b(v);
}

__global__ void prep_bias_kernel(const float* __restrict__ Wself, const float* __restrict__ b,
                                 const float* __restrict__ st, float* __restrict__ biasp) {
    int rel = blockIdx.x, c = threadIdx.x;
    const float* t = st + rel * 2 * H + H;
    float s = b[rel * H + c];
    for (int k = 0; k < H; k++) s += t[k] * Wself[((size_t)rel * H + k) * H + c];
    biasp[rel * H + c] = s;
}

// ---------------- Readout: per-graph sums of raw hp ----------------

__global__ __launch_bounds__(256) void readout_kernel(
        const unsigned short* __restrict__ hp, const int* __restrict__ seg,
        float* __restrict__ out, int layer) {
    int rel = blockIdx.y;
    int c8 = (threadIdx.x & 15) * 8;
    int roff = threadIdx.x >> 4;  // 0..15
    int row0 = blockIdx.x * 256;
    const unsigned short* h = hp + (size_t)rel * N_NODES * H;
    const int* sg = seg + rel * N_NODES;
    int curg = -1;
    float run[8];
#pragma unroll
    for (int j = 0; j < 8; j++) run[j] = 0.f;
    int rend = min(row0 + 256, N_NODES);
    for (int r = row0 + roff; r < rend; r += 16) {
        uint4 v = *(const uint4*)&h[(size_t)r * H + c8];
        unsigned int w[4] = {v.x, v.y, v.z, v.w};
        int g = sg[r];
        if (g != curg) {
            if (curg >= 0) {
                float* ob = out + curg * (3 * 4 * H) + rel * (4 * H) + layer * H + c8;
#pragma unroll
                for (int j = 0; j < 8; j++) atomicAdd(ob + j, run[j]);
            }
            curg = g;
#pragma unroll
            for (int j = 0; j < 8; j++) run[j] = 0.f;
        }
#pragma unroll
        for (int j = 0; j < 4; j++) {
            run[2 * j] += __builtin_bit_cast(float, w[j] << 16);
            run[2 * j + 1] += __builtin_bit_cast(float, w[j] & 0xffff0000u);
        }
    }
    if (curg >= 0) {
        float* ob = out + curg * (3 * 4 * H) + rel * (4 * H) + layer * H + c8;
#pragma unroll
        for (int j = 0; j < 8; j++) atomicAdd(ob + j, run[j]);
    }
}

// ---------------- Final: mean + BN affine ----------------

__global__ void scale_out_kernel(float* __restrict__ out, const int* __restrict__ seg,
                                 const float* __restrict__ st_all) {
    int i = blockIdx.x * 256 + threadIdx.x;
    if (i >= N_GRAPHS * 3 * 4 * H) return;
    int g = i / (3 * 4 * H), k = i % (3 * 4 * H);
    int rel = k / (4 * H), rem = k % (4 * H), layer = rem / H, c = rem % H;
    const int* sg = seg + rel * N_NODES;
    int lo = 0, hi = N_NODES;
    while (lo < hi) { int m = (lo + hi) >> 1; if (sg[m] < g) lo = m + 1; else hi = m; }
    int start = lo;
    hi = N_NODES;
    while (lo < hi) { int m = (lo + hi) >> 1; if (sg[m] <= g) lo = m + 1; else hi = m; }
    int cnt = lo - start;
    float mean = out[i] / (float)max(cnt, 1);
    const float* st = st_all + ((size_t)layer * 3 + rel) * 2 * H;
    out[i] = st[c] * mean + st[H + c];
}

// ---------------- Orchestration ----------------

extern "C" void kernel_launch(void* const* d_in, const int* in_sizes, int n_in,
                              void* d_out, int out_size, void* d_ws, size_t ws_size,
                              hipStream_t stream) {
    const int* h_idx = (const int*)d_in[0];
    const int* p_idx = (const int*)d_in[1];
    const int* hp_idx = (const int*)d_in[2];
    const int* src = (const int*)d_in[3];
    const int* dst = (const int*)d_in[4];
    const int* seg = (const int*)d_in[5];
    const float* emb_h = (const float*)d_in[6];
    const float* emb_p = (const float*)d_in[7];
    const float* emb_hp = (const float*)d_in[8];
    const float* W1_self = (const float*)d_in[9];
    const float* W1_neigh = (const float*)d_in[10];
    const float* b1 = (const float*)d_in[11];
    const float* a1 = (const float*)d_in[12];
    const float* gamma1 = (const float*)d_in[13];
    const float* beta1 = (const float*)d_in[14];
    const float* W_self = (const float*)d_in[15];
    const float* W_neigh = (const float*)d_in[16];
    const float* b = (const float*)d_in[17];
    const float* a = (const float*)d_in[18];
    const float* gamma = (const float*)d_in[19];
    const float* beta = (const float*)d_in[20];
    float* out = (float*)d_out;

    // workspace
    char* p = (char*)d_ws;
    unsigned short* x0 = (unsigned short*)p; p += (size_t)3 * N_NODES * EMB * 2;   // 19.2 MB
    unsigned short* hpA = (unsigned short*)p; p += (size_t)3 * N_NODES * H * 2;    // 38.4 MB
    unsigned short* hpB = (unsigned short*)p; p += (size_t)3 * N_NODES * H * 2;    // 38.4 MB
    unsigned short* Wbt1 = (unsigned short*)p; p += (size_t)3 * H * 128 * 2;
    unsigned short* Wbt = (unsigned short*)p; p += (size_t)3 * H * 256 * 2;
    float* biasp = (float*)p; p += 3 * H * sizeof(float);
    float* st_all = (float*)p; p += 4 * 3 * 2 * H * sizeof(float);
    float* stats = (float*)p; p += 3 * 256 * sizeof(float);
    int* deg = (int*)p; p += (size_t)3 * N_NODES * 4;
    int* row_ptr = (int*)p; p += (size_t)3 * (N_NODES + 1) * 4;
    int* cur = (int*)p; p += (size_t)3 * N_NODES * 4;
    int* edge_src = (int*)p; p += (size_t)3 * N_EDGES * 4;

    hipMemsetAsync(out, 0, (size_t)N_GRAPHS * 3 * 4 * H * sizeof(float), stream);

    // CSR build
    hipMemsetAsync(deg, 0, (size_t)3 * N_NODES * 4, stream);
    dim3 eb((N_EDGES + 255) / 256, 3);
    count_deg_kernel<<<eb, 256, 0, stream>>>(dst, deg);
    scan_kernel<<<3, 1024, 0, stream>>>(deg, row_ptr);
    init_cur_kernel<<<(3 * N_NODES + 255) / 256, 256, 0, stream>>>(row_ptr, cur);
    fill_kernel<<<eb, 256, 0, stream>>>(src, dst, cur, edge_src);

    embed_kernel<<<dim3((N_NODES * EMB / 8 + 255) / 256, 3), 256, 0, stream>>>(
        h_idx, p_idx, hp_idx, emb_h, emb_p, emb_hp, x0);
    prep1_kernel<<<(3 * H * 128 + 255) / 256, 256, 0, stream>>>(W1_self, W1_neigh, Wbt1);

    dim3 gemm_grid((N_NODES + 127) / 128, 3);
    dim3 ro_grid((N_NODES + 255) / 256, 3);

    // ---- layer 1 (K = 64, no fold) ----
    hipMemsetAsync(stats, 0, 3 * 256 * 4, stream);
    fused_gemm_kernel<64, false><<<gemm_grid, 256, 0, stream>>>(
        x0, row_ptr, edge_src, nullptr, Wbt1, b1, a1, hpA, stats);
    finalize_kernel<<<3, H, 0, stream>>>(stats, gamma1, beta1, st_all);
    readout_kernel<<<ro_grid, 256, 0, stream>>>(hpA, seg, out, 0);

    // ---- layers 2-4 (K = 128, fold st of previous BN) ----
    unsigned short* xin = hpA;
    unsigned short* xout = hpB;
    for (int l = 0; l < 3; l++) {
        const float* st_prev = st_all + (size_t)l * 3 * 2 * H;
        prep_w_kernel<<<(3 * H * 256 + 255) / 256, 256, 0, stream>>>(
            W_self + (size_t)l * 3 * H * H, W_neigh + (size_t)l * 3 * H * H, st_prev, Wbt);
        prep_bias_kernel<<<3, H, 0, stream>>>(
            W_self + (size_t)l * 3 * H * H, b + (size_t)l * 3 * H, st_prev, biasp);
        hipMemsetAsync(stats, 0, 3 * 256 * 4, stream);
        fused_gemm_kernel<128, true><<<gemm_grid, 256, 0, stream>>>(
            xin, row_ptr, edge_src, st_prev, Wbt, biasp, a + (size_t)l * 3 * H, xout, stats);
        finalize_kernel<<<3, H, 0, stream>>>(
            stats, gamma + (size_t)l * 3 * H, beta + (size_t)l * 3 * H,
            st_all + (size_t)(l + 1) * 3 * 2 * H);
        readout_kernel<<<ro_grid, 256, 0, stream>>>(xout, seg, out, l + 1);
        unsigned short* t = xin; xin = xout; xout = t;
    }

    scale_out_kernel<<<(N_GRAPHS * 3 * 4 * H + 255) / 256, 256, 0, stream>>>(out, seg, st_all);
}

// Round 6
// 793.624 us; speedup vs baseline: 1.5072x; 1.5072x over previous
//
#include <hip/hip_runtime.h>

#define N_NODES 50000
#define N_EDGES 400000
#define N_GRAPHS 64
#define EMB 64
#define H 128
#define EPS 1e-5f

typedef __attribute__((ext_vector_type(8))) short bf16x8;
typedef __attribute__((ext_vector_type(4))) float f32x4;

__device__ __forceinline__ unsigned short f2b(float f) {
    unsigned int u = __builtin_bit_cast(unsigned int, f);
    unsigned int r = (u + 0x7fff + ((u >> 16) & 1)) >> 16;  // RNE
    return (unsigned short)r;
}

// ---------------- CSR build ----------------

__global__ void count_deg_kernel(const int* __restrict__ dst, int* __restrict__ deg) {
    int rel = blockIdx.y;
    int e = blockIdx.x * 256 + threadIdx.x;
    if (e < N_EDGES) atomicAdd(&deg[rel * N_NODES + dst[rel * N_EDGES + e]], 1);
}

// 4 elems/thread, 4096/chunk -> 13 chunks
__global__ void scan_kernel(const int* __restrict__ deg, int* __restrict__ row_ptr) {
    int rel = blockIdx.x;
    const int* d = deg + rel * N_NODES;
    int* rp = row_ptr + rel * (N_NODES + 1);
    __shared__ int sm[1024];
    __shared__ int carry;
    if (threadIdx.x == 0) carry = 0;
    __syncthreads();
    for (int base = 0; base < N_NODES; base += 4096) {
        int i0 = base + (int)threadIdx.x * 4;
        int v[4];
        int s = 0;
#pragma unroll
        for (int k = 0; k < 4; k++) { v[k] = (i0 + k < N_NODES) ? d[i0 + k] : 0; s += v[k]; }
        sm[threadIdx.x] = s;
        __syncthreads();
        for (int off = 1; off < 1024; off <<= 1) {
            int t = (threadIdx.x >= off) ? sm[threadIdx.x - off] : 0;
            __syncthreads();
            sm[threadIdx.x] += t;
            __syncthreads();
        }
        int run = carry + sm[threadIdx.x] - s;  // exclusive for first elem
#pragma unroll
        for (int k = 0; k < 4; k++) {
            if (i0 + k < N_NODES) rp[i0 + k] = run;
            run += v[k];
        }
        __syncthreads();  // all carry reads done
        if (threadIdx.x == 1023) carry += sm[1023];
        __syncthreads();
    }
    if (threadIdx.x == 0) rp[N_NODES] = carry;
}

__global__ void init_cur_kernel(const int* __restrict__ row_ptr, int* __restrict__ cur) {
    int i = blockIdx.x * 256 + threadIdx.x;
    if (i < 3 * N_NODES) {
        int rel = i / N_NODES, n = i - rel * N_NODES;
        cur[i] = row_ptr[rel * (N_NODES + 1) + n];
    }
}

__global__ void fill_kernel(const int* __restrict__ src, const int* __restrict__ dst,
                            int* __restrict__ cur, int* __restrict__ edge_src) {
    int rel = blockIdx.y;
    int e = blockIdx.x * 256 + threadIdx.x;
    if (e < N_EDGES) {
        int dn = dst[rel * N_EDGES + e];
        int pos = atomicAdd(&cur[rel * N_NODES + dn], 1);
        edge_src[rel * N_EDGES + pos] = src[rel * N_EDGES + e];
    }
}

// ---------------- Embedding gather -> bf16 x0 ----------------

__global__ void embed_kernel(const int* __restrict__ h_idx, const int* __restrict__ p_idx,
                             const int* __restrict__ hp_idx,
                             const float* __restrict__ emb_h, const float* __restrict__ emb_p,
                             const float* __restrict__ emb_hp,
                             unsigned short* __restrict__ x) {
    int rel = blockIdx.y;
    int i = blockIdx.x * 256 + threadIdx.x;  // 8-col units
    if (i >= N_NODES * EMB / 8) return;
    int n = i / (EMB / 8), c8 = (i % (EMB / 8)) * 8;
    const int* idx = rel == 0 ? h_idx : (rel == 1 ? p_idx : hp_idx);
    const float* emb = rel == 0 ? emb_h : (rel == 1 ? emb_p : emb_hp);
    const float* e = emb + (size_t)idx[n] * EMB + c8;
    unsigned short o[8];
#pragma unroll
    for (int j = 0; j < 8; j++) o[j] = f2b(e[j]);
    *(uint4*)&x[(size_t)rel * N_NODES * EMB + (size_t)n * EMB + c8] = *(uint4*)o;
}

// ---------------- Neighbor mean aggregation (bf16 gather, BN-affine fold) ----------------
// Output nmean has ld = DIN. deg==0 -> exact 0 (reference semantics).

template <int DIN, bool FOLD>
__global__ __launch_bounds__(256) void aggregate_kernel(
        const unsigned short* __restrict__ x, int ldx,
        const int* __restrict__ row_ptr, const int* __restrict__ edge_src,
        const float* __restrict__ st,
        unsigned short* __restrict__ nmean) {
    const int TPN = DIN / 8;
    int rel = blockIdx.y;
    int node = blockIdx.x * (256 / TPN) + threadIdx.x / TPN;
    int c8 = (threadIdx.x % TPN) * 8;
    if (node >= N_NODES) return;
    const int* rp = row_ptr + rel * (N_NODES + 1);
    const int* es = edge_src + rel * N_EDGES;
    const unsigned short* xr = x + (size_t)rel * N_NODES * ldx;
    int s0 = rp[node], s1 = rp[node + 1];
    float acc[8];
#pragma unroll
    for (int j = 0; j < 8; j++) acc[j] = 0.f;

#define ACCUM(V)                                                                      \
    {                                                                                 \
        unsigned int w[4] = {(V).x, (V).y, (V).z, (V).w};                             \
        _Pragma("unroll") for (int j = 0; j < 4; j++) {                               \
            acc[2 * j] += __builtin_bit_cast(float, w[j] << 16);                      \
            acc[2 * j + 1] += __builtin_bit_cast(float, w[j] & 0xffff0000u);          \
        }                                                                             \
    }

    int e = s0;
    for (; e + 8 <= s1; e += 8) {
        int i0 = es[e], i1 = es[e + 1], i2 = es[e + 2], i3 = es[e + 3];
        int i4 = es[e + 4], i5 = es[e + 5], i6 = es[e + 6], i7 = es[e + 7];
        uint4 v0 = *(const uint4*)&xr[(size_t)i0 * ldx + c8];
        uint4 v1 = *(const uint4*)&xr[(size_t)i1 * ldx + c8];
        uint4 v2 = *(const uint4*)&xr[(size_t)i2 * ldx + c8];
        uint4 v3 = *(const uint4*)&xr[(size_t)i3 * ldx + c8];
        uint4 v4 = *(const uint4*)&xr[(size_t)i4 * ldx + c8];
        uint4 v5 = *(const uint4*)&xr[(size_t)i5 * ldx + c8];
        uint4 v6 = *(const uint4*)&xr[(size_t)i6 * ldx + c8];
        uint4 v7 = *(const uint4*)&xr[(size_t)i7 * ldx + c8];
        ACCUM(v0) ACCUM(v1) ACCUM(v2) ACCUM(v3)
        ACCUM(v4) ACCUM(v5) ACCUM(v6) ACCUM(v7)
    }
    for (; e + 4 <= s1; e += 4) {
        int i0 = es[e], i1 = es[e + 1], i2 = es[e + 2], i3 = es[e + 3];
        uint4 v0 = *(const uint4*)&xr[(size_t)i0 * ldx + c8];
        uint4 v1 = *(const uint4*)&xr[(size_t)i1 * ldx + c8];
        uint4 v2 = *(const uint4*)&xr[(size_t)i2 * ldx + c8];
        uint4 v3 = *(const uint4*)&xr[(size_t)i3 * ldx + c8];
        ACCUM(v0) ACCUM(v1) ACCUM(v2) ACCUM(v3)
    }
    for (; e < s1; e++) {
        uint4 v0 = *(const uint4*)&xr[(size_t)es[e] * ldx + c8];
        ACCUM(v0)
    }
#undef ACCUM
    int deg = s1 - s0;
    float inv = 1.f / (float)max(deg, 1);
    unsigned short o[8];
#pragma unroll
    for (int j = 0; j < 8; j++) {
        float m = acc[j] * inv;
        if (FOLD) {
            float s = st[rel * 2 * H + c8 + j];
            float t = st[rel * 2 * H + H + c8 + j];
            m = s * m + t;
        }
        o[j] = (deg > 0) ? f2b(m) : (unsigned short)0;
    }
    *(uint4*)&nmean[((size_t)rel * N_NODES + node) * DIN + c8] = *(uint4*)o;
}

// ---- MFMA GEMM: hp = PReLU([x | nmean] @ Wbt^T + bias); fp32 col stats;
//      per-graph readout sums fused into epilogue (seg sorted per rel). ----

template <int KX>
__global__ __launch_bounds__(256) void gemm_kernel(
        const unsigned short* __restrict__ x,      // [rel][N][KX] bf16 self input
        const unsigned short* __restrict__ nmean,  // [rel][N][KX] bf16
        const unsigned short* __restrict__ Wbt,    // [rel][H cols][2*KX] bf16
        const float* __restrict__ bias,            // [rel][H]
        const float* __restrict__ alpha,           // [rel][H]
        unsigned short* __restrict__ out,          // [rel][N][H] bf16 (pre-BN)
        float* __restrict__ stats,
        const int* __restrict__ seg_all,           // [rel][N] sorted graph ids
        float* __restrict__ gout,                  // [G][3][4][H] sum accumulator
        int layer) {
    const int KTOT = 2 * KX;
    int rel = blockIdx.y;
    int row0 = blockIdx.x * 128;
    const unsigned short* xr = x + (size_t)rel * N_NODES * KX;
    const unsigned short* nm = nmean + (size_t)rel * N_NODES * KX;
    const unsigned short* W = Wbt + (size_t)rel * H * KTOT;
    unsigned short* o = out + (size_t)rel * N_NODES * H;

    __shared__ __align__(16) short At[128][40];
    __shared__ __align__(16) short Bt[128][40];

    int tid = threadIdx.x;
    int lane = tid & 63;
    int wave = tid >> 6;
    int wr = wave >> 1, wc = wave & 1;
    int l15 = lane & 15;
    int koff = (lane >> 4) * 8;

    f32x4 acc[4][4];
#pragma unroll
    for (int m = 0; m < 4; m++)
#pragma unroll
        for (int n = 0; n < 4; n++) acc[m][n] = (f32x4){0.f, 0.f, 0.f, 0.f};

    int seg = tid & 3;
    int rloc = tid >> 2;

    for (int kc = 0; kc < KTOT; kc += 32) {
        const unsigned short* Asrc;
        int kb;
        if (kc < KX) { Asrc = xr; kb = kc; }
        else         { Asrc = nm; kb = kc - KX; }
#pragma unroll
        for (int i = 0; i < 2; i++) {
            int r = i * 64 + rloc;
            int gr = row0 + r;
            uint4 v = make_uint4(0u, 0u, 0u, 0u);
            if (gr < N_NODES) v = *(const uint4*)&Asrc[(size_t)gr * KX + kb + seg * 8];
            *(uint4*)&At[r][seg * 8] = v;
        }
#pragma unroll
        for (int i = 0; i < 2; i++) {
            int c = i * 64 + rloc;
            *(uint4*)&Bt[c][seg * 8] = *(const uint4*)&W[(size_t)c * KTOT + kc + seg * 8];
        }
        __syncthreads();
        bf16x8 a[4], b[4];
#pragma unroll
        for (int m = 0; m < 4; m++) a[m] = *(const bf16x8*)&At[wr * 64 + m * 16 + l15][koff];
#pragma unroll
        for (int n = 0; n < 4; n++) b[n] = *(const bf16x8*)&Bt[wc * 64 + n * 16 + l15][koff];
#pragma unroll
        for (int m = 0; m < 4; m++)
#pragma unroll
            for (int n = 0; n < 4; n++)
                acc[m][n] = __builtin_amdgcn_mfma_f32_16x16x32_bf16(a[m], b[n], acc[m][n], 0, 0, 0);
        __syncthreads();
    }

    // epilogue: bias + PReLU, bf16 store, fp32 column stats, per-graph run sums
    float bs[4], as_[4];
#pragma unroll
    for (int n = 0; n < 4; n++) {
        int col = wc * 64 + n * 16 + l15;
        bs[n] = bias[rel * H + col];
        as_[n] = alpha[rel * H + col];
    }
    const int* sg = seg_all + rel * N_NODES;
    float csum[4] = {0.f, 0.f, 0.f, 0.f}, cssq[4] = {0.f, 0.f, 0.f, 0.f};
    int curg = -1;
    float run[4] = {0.f, 0.f, 0.f, 0.f};
    int rbase = row0 + wr * 64 + (lane >> 4) * 4;
#pragma unroll
    for (int m = 0; m < 4; m++) {
#pragma unroll
        for (int j = 0; j < 4; j++) {
            int r = rbase + m * 16 + j;
            if (r >= N_NODES) continue;
            int g = sg[r];
            if (g != curg) {
                if (curg >= 0) {
                    float* ob = gout + (size_t)curg * (3 * 4 * H) + rel * (4 * H) + layer * H + wc * 64 + l15;
#pragma unroll
                    for (int n = 0; n < 4; n++) { atomicAdd(ob + n * 16, run[n]); run[n] = 0.f; }
                }
                curg = g;
            }
#pragma unroll
            for (int n = 0; n < 4; n++) {
                float v = acc[m][n][j] + bs[n];
                v = v > 0.f ? v : as_[n] * v;
                o[(size_t)r * H + wc * 64 + n * 16 + l15] = f2b(v);
                csum[n] += v;
                cssq[n] += v * v;
                run[n] += v;
            }
        }
    }
    if (curg >= 0) {
        float* ob = gout + (size_t)curg * (3 * 4 * H) + rel * (4 * H) + layer * H + wc * 64 + l15;
#pragma unroll
        for (int n = 0; n < 4; n++) atomicAdd(ob + n * 16, run[n]);
    }
    __syncthreads();
    float* smS = (float*)&At[0][0];   // 128 cols x 8 contributors = 4 KB
    float* smQ = (float*)&Bt[0][0];
    int contrib = wr * 4 + (lane >> 4);
#pragma unroll
    for (int n = 0; n < 4; n++) {
        int col = wc * 64 + n * 16 + l15;
        smS[col * 8 + contrib] = csum[n];
        smQ[col * 8 + contrib] = cssq[n];
    }
    __syncthreads();
    if (tid < 128) {
        float s = 0.f, q = 0.f;
#pragma unroll
        for (int i = 0; i < 8; i++) { s += smS[tid * 8 + i]; q += smQ[tid * 8 + i]; }
        atomicAdd(&stats[rel * 256 + tid], s);
        atomicAdd(&stats[rel * 256 + 128 + tid], q);
    }
}

// ---------------- BN stats -> affine (s,t); self-zero stats for next layer ----------------

__global__ void finalize_kernel(float* __restrict__ stats,
                                const float* __restrict__ gamma, const float* __restrict__ beta,
                                float* __restrict__ st) {
    int rel = blockIdx.x, c = threadIdx.x;
    const float invN = 1.f / N_NODES;
    float mu = stats[rel * 256 + c] * invN;
    float var = stats[rel * 256 + 128 + c] * invN - mu * mu;
    float s = gamma[rel * H + c] * rsqrtf(var + EPS);
    st[rel * 2 * H + c] = s;
    st[rel * 2 * H + H + c] = beta[rel * H + c] - mu * s;
    stats[rel * 256 + c] = 0.f;
    stats[rel * 256 + 128 + c] = 0.f;
}

// ---------------- Weight prep ----------------

__global__ void prep1_kernel(const float* __restrict__ Wself, const float* __restrict__ Wneigh,
                             unsigned short* __restrict__ Wbt) {
    int idx = blockIdx.x * 256 + threadIdx.x;
    if (idx >= 3 * H * 128) return;
    int rel = idx / (H * 128), rem = idx % (H * 128);
    int c = rem / 128, k = rem % 128;
    float v = (k < 64) ? Wself[((size_t)rel * 64 + k) * H + c]
                       : Wneigh[((size_t)rel * 64 + (k - 64)) * H + c];
    Wbt[idx] = f2b(v);
}

// merged: blocks 0..383 -> W fold/convert; blocks 384..386 -> bias fold
__global__ void prep_kernel(const float* __restrict__ Wself, const float* __restrict__ Wneigh,
                            const float* __restrict__ b, const float* __restrict__ st,
                            unsigned short* __restrict__ Wbt, float* __restrict__ biasp) {
    if (blockIdx.x < 384) {
        int idx = blockIdx.x * 256 + threadIdx.x;
        int rel = idx / (H * 256), rem = idx % (H * 256);
        int c = rem / 256, k = rem % 256;
        float v;
        if (k < 128) v = st[rel * 2 * H + k] * Wself[((size_t)rel * H + k) * H + c];
        else         v = Wneigh[((size_t)rel * H + (k - 128)) * H + c];
        Wbt[idx] = f2b(v);
    } else if (threadIdx.x < H) {
        int rel = blockIdx.x - 384, c = threadIdx.x;
        const float* t = st + rel * 2 * H + H;
        float s = b[rel * H + c];
        for (int k = 0; k < H; k++) s += t[k] * Wself[((size_t)rel * H + k) * H + c];
        biasp[rel * H + c] = s;
    }
}

// ---------------- Final: mean + BN affine ----------------

__global__ void scale_out_kernel(float* __restrict__ out, const int* __restrict__ seg,
                                 const float* __restrict__ st_all) {
    int i = blockIdx.x * 256 + threadIdx.x;
    if (i >= N_GRAPHS * 3 * 4 * H) return;
    int g = i / (3 * 4 * H), k = i % (3 * 4 * H);
    int rel = k / (4 * H), rem = k % (4 * H), layer = rem / H, c = rem % H;
    const int* sg = seg + rel * N_NODES;
    int lo = 0, hi = N_NODES;
    while (lo < hi) { int m = (lo + hi) >> 1; if (sg[m] < g) lo = m + 1; else hi = m; }
    int start = lo;
    hi = N_NODES;
    while (lo < hi) { int m = (lo + hi) >> 1; if (sg[m] <= g) lo = m + 1; else hi = m; }
    int cnt = lo - start;
    float mean = out[i] / (float)max(cnt, 1);
    const float* st = st_all + ((size_t)layer * 3 + rel) * 2 * H;
    out[i] = st[c] * mean + st[H + c];
}

// ---------------- Orchestration ----------------

extern "C" void kernel_launch(void* const* d_in, const int* in_sizes, int n_in,
                              void* d_out, int out_size, void* d_ws, size_t ws_size,
                              hipStream_t stream) {
    const int* h_idx = (const int*)d_in[0];
    const int* p_idx = (const int*)d_in[1];
    const int* hp_idx = (const int*)d_in[2];
    const int* src = (const int*)d_in[3];
    const int* dst = (const int*)d_in[4];
    const int* seg = (const int*)d_in[5];
    const float* emb_h = (const float*)d_in[6];
    const float* emb_p = (const float*)d_in[7];
    const float* emb_hp = (const float*)d_in[8];
    const float* W1_self = (const float*)d_in[9];
    const float* W1_neigh = (const float*)d_in[10];
    const float* b1 = (const float*)d_in[11];
    const float* a1 = (const float*)d_in[12];
    const float* gamma1 = (const float*)d_in[13];
    const float* beta1 = (const float*)d_in[14];
    const float* W_self = (const float*)d_in[15];
    const float* W_neigh = (const float*)d_in[16];
    const float* b = (const float*)d_in[17];
    const float* a = (const float*)d_in[18];
    const float* gamma = (const float*)d_in[19];
    const float* beta = (const float*)d_in[20];
    float* out = (float*)d_out;

    // workspace
    char* p = (char*)d_ws;
    unsigned short* x0 = (unsigned short*)p; p += (size_t)3 * N_NODES * EMB * 2;   // 19.2 MB
    unsigned short* hpA = (unsigned short*)p; p += (size_t)3 * N_NODES * H * 2;    // 38.4 MB
    unsigned short* hpB = (unsigned short*)p; p += (size_t)3 * N_NODES * H * 2;    // 38.4 MB
    unsigned short* Wbt1 = (unsigned short*)p; p += (size_t)3 * H * 128 * 2;
    unsigned short* Wbt = (unsigned short*)p; p += (size_t)3 * H * 256 * 2;
    float* biasp = (float*)p; p += 3 * H * sizeof(float);
    float* st_all = (float*)p; p += 4 * 3 * 2 * H * sizeof(float);
    float* stats = (float*)p; p += 3 * 256 * sizeof(float);
    int* deg = (int*)p; p += (size_t)3 * N_NODES * 4;
    int* row_ptr = (int*)p; p += (size_t)3 * (N_NODES + 1) * 4;
    int* cur = (int*)p; p += (size_t)3 * N_NODES * 4;
    int* edge_src = (int*)p; p += (size_t)3 * N_EDGES * 4;

    hipMemsetAsync(out, 0, (size_t)N_GRAPHS * 3 * 4 * H * sizeof(float), stream);
    hipMemsetAsync(stats, 0, 3 * 256 * 4, stream);

    // CSR build
    hipMemsetAsync(deg, 0, (size_t)3 * N_NODES * 4, stream);
    dim3 eb((N_EDGES + 255) / 256, 3);
    count_deg_kernel<<<eb, 256, 0, stream>>>(dst, deg);
    scan_kernel<<<3, 1024, 0, stream>>>(deg, row_ptr);
    init_cur_kernel<<<(3 * N_NODES + 255) / 256, 256, 0, stream>>>(row_ptr, cur);
    fill_kernel<<<eb, 256, 0, stream>>>(src, dst, cur, edge_src);

    embed_kernel<<<dim3((N_NODES * EMB / 8 + 255) / 256, 3), 256, 0, stream>>>(
        h_idx, p_idx, hp_idx, emb_h, emb_p, emb_hp, x0);
    prep1_kernel<<<(3 * H * 128 + 255) / 256, 256, 0, stream>>>(W1_self, W1_neigh, Wbt1);

    dim3 gemm_grid((N_NODES + 127) / 128, 3);

    // ---- layer 1 (K = 64; nmean ld=64 in hpB; out hpA) ----
    aggregate_kernel<64, false><<<dim3((N_NODES + 31) / 32, 3), 256, 0, stream>>>(
        x0, EMB, row_ptr, edge_src, nullptr, hpB);
    gemm_kernel<64><<<gemm_grid, 256, 0, stream>>>(
        x0, hpB, Wbt1, b1, a1, hpA, stats, seg, out, 0);
    finalize_kernel<<<3, H, 0, stream>>>(stats, gamma1, beta1, st_all);

    // ---- layers 2-4 (K = 128; out aliases nmean) ----
    unsigned short* xin = hpA;
    unsigned short* xout = hpB;
    for (int l = 0; l < 3; l++) {
        const float* st_prev = st_all + (size_t)l * 3 * 2 * H;
        prep_kernel<<<387, 256, 0, stream>>>(
            W_self + (size_t)l * 3 * H * H, W_neigh + (size_t)l * 3 * H * H,
            b + (size_t)l * 3 * H, st_prev, Wbt, biasp);
        aggregate_kernel<128, true><<<dim3((N_NODES + 15) / 16, 3), 256, 0, stream>>>(
            xin, H, row_ptr, edge_src, st_prev, xout);
        gemm_kernel<128><<<gemm_grid, 256, 0, stream>>>(
            xin, xout, Wbt, biasp, a + (size_t)l * 3 * H, xout, stats, seg, out, l + 1);
        finalize_kernel<<<3, H, 0, stream>>>(
            stats, gamma + (size_t)l * 3 * H, beta + (size_t)l * 3 * H,
            st_all + (size_t)(l + 1) * 3 * 2 * H);
        unsigned short* t = xin; xin = xout; xout = t;
    }

    scale_out_kernel<<<(N_GRAPHS * 3 * 4 * H + 255) / 256, 256, 0, stream>>>(out, seg, st_all);
}